// Round 4
// baseline (390.092 us; speedup 1.0000x reference)
//
#include <hip/hip_runtime.h>
#include <hip/hip_bf16.h>
#include <cstdint>

typedef __bf16 bf16x8 __attribute__((ext_vector_type(8)));
typedef __bf16 bf16x4 __attribute__((ext_vector_type(4)));
typedef float  f32x4  __attribute__((ext_vector_type(4)));

#define ND 128
#define HID 128

__device__ __forceinline__ f32x4 mfma_bf16(bf16x8 a, bf16x8 b, f32x4 c) {
  return __builtin_amdgcn_mfma_f32_16x16x32_bf16(a, b, c, 0, 0, 0);
}
__device__ __forceinline__ float fast_sigmoid(float x) {
  return __fdividef(1.f, 1.f + __expf(-x));
}
__device__ __forceinline__ float fast_silu(float x) {
  return __fdividef(x, 1.f + __expf(-x));
}
__device__ __forceinline__ float fast_tanh(float x) {
  float cx = fminf(fmaxf(x, -15.f), 15.f);
  float e = __expf(2.f * cx);
  return __fdividef(e - 1.f, e + 1.f);
}

// ---- fused f32 -> bf16 conversion over 5 segments ----
__global__ void cvt_all(const float* __restrict__ s0, __bf16* __restrict__ d0, int c1,
                        const float* __restrict__ s1, __bf16* __restrict__ d1, int c2,
                        const float* __restrict__ s2, __bf16* __restrict__ d2, int c3,
                        const float* __restrict__ s3, __bf16* __restrict__ d3, int c4,
                        const float* __restrict__ s4, __bf16* __restrict__ d4, int c5) {
  int i = blockIdx.x * blockDim.x + threadIdx.x;
  const float* s; __bf16* d; int j;
  if (i < c1)      { s = s0; d = d0; j = i; }
  else if (i < c2) { s = s1; d = d1; j = i - c1; }
  else if (i < c3) { s = s2; d = d2; j = i - c2; }
  else if (i < c4) { s = s3; d = d3; j = i - c3; }
  else if (i < c5) { s = s4; d = d4; j = i - c4; }
  else return;
  const float4* sp = reinterpret_cast<const float4*>(s) + (size_t)j * 2;
  float4 a = sp[0], b = sp[1];
  bf16x8 v;
  v[0] = (__bf16)a.x; v[1] = (__bf16)a.y; v[2] = (__bf16)a.z; v[3] = (__bf16)a.w;
  v[4] = (__bf16)b.x; v[5] = (__bf16)b.y; v[6] = (__bf16)b.z; v[7] = (__bf16)b.w;
  reinterpret_cast<bf16x8*>(d)[j] = v;
}

// ================= sort machinery =================
__global__ void k_hist(const int* __restrict__ dst, int* __restrict__ counts, int E) {
  int e = blockIdx.x * 256 + threadIdx.x;
  if (e < E) atomicAdd(&counts[dst[e]], 1);
}

__global__ void k_blocksum(const int* __restrict__ counts, int* __restrict__ bsum) {
  __shared__ int sd[256];
  int t = threadIdx.x;
  sd[t] = counts[blockIdx.x * 256 + t];
  __syncthreads();
  for (int d = 128; d > 0; d >>= 1) { if (t < d) sd[t] += sd[t + d]; __syncthreads(); }
  if (!t) bsum[blockIdx.x] = sd[0];
}

__global__ void k_scan_bsum(int* __restrict__ bsum, int nb) {
  __shared__ int sd[256];
  int t = threadIdx.x;
  int v = (t < nb) ? bsum[t] : 0;
  sd[t] = v;
  __syncthreads();
  for (int d = 1; d < 256; d <<= 1) {
    int u = (t >= d) ? sd[t - d] : 0;
    __syncthreads();
    sd[t] += u;
    __syncthreads();
  }
  if (t < nb) bsum[t] = sd[t] - v;
}

__global__ void k_scan_write(const int* __restrict__ counts, const int* __restrict__ bsum,
                             int* __restrict__ offsets, int* __restrict__ cursor) {
  __shared__ int sd[256];
  int t = threadIdx.x, b = blockIdx.x;
  int i = b * 256 + t;
  int c = counts[i];
  sd[t] = c;
  __syncthreads();
  for (int d = 1; d < 256; d <<= 1) {
    int u = (t >= d) ? sd[t - d] : 0;
    __syncthreads();
    sd[t] += u;
    __syncthreads();
  }
  int excl = bsum[b] + sd[t] - c;
  offsets[i] = excl;
  cursor[i]  = excl;
  if (b == (int)gridDim.x - 1 && t == 255) offsets[i + 1] = excl + c;
}

__global__ void k_spos(const int* __restrict__ dst, int* __restrict__ cursor,
                       int* __restrict__ spos, int E) {
  int e = blockIdx.x * 256 + threadIdx.x;
  if (e < E) spos[e] = atomicAdd(&cursor[dst[e]], 1);
}

// ================= edge MLP (weights-as-A, transposed output) =================
// 512 threads = 8 waves, each wave owns a 16-wide j-strip. TILE_E=64.
// A tile rows: 384B (24 chunks of 16B), XOR-swizzled by (e&7); spos stashed in
// the per-row free chunk (20^sw). H1 rows: 256B (16 chunks), same swizzle.
// LDS total = 64*384 + 64*256 = 40960 B -> up to 4 blocks/CU.
#define TILE_E 64

template <int SORT>
__global__ __launch_bounds__(512, 6) void edge_mlp(
    const __bf16* __restrict__ xb,
    const int*    __restrict__ ei,     // [2*E]: src then dst
    const float*  __restrict__ ea,     // [E,32]
    const __bf16* __restrict__ W1b,    // [128,160]
    const float*  __restrict__ b1,
    const __bf16* __restrict__ W2b,    // [128,128]
    const float*  __restrict__ b2,
    float*  __restrict__ agg,          // SORT==0
    __bf16* __restrict__ mbuf,         // SORT==1
    const int* __restrict__ spos,
    int E, int ntiles)
{
  __shared__ __bf16 Als[TILE_E * 192];
  __shared__ __bf16 H1[TILE_E * 128];
  char* AlsB = (char*)Als;
  char* H1B  = (char*)H1;

  const int tid = threadIdx.x;
  const int w  = tid >> 6;      // wave 0..7 -> j-strip of 16
  const int l  = tid & 63;
  const int l4 = l >> 4;
  const int lm = l & 15;
  const int jb = w * 16;

  // Weight fragments (A-operand): row jr = jb + lm, k = kt*32 + l4*8
  bf16x8 bw1[5], bw2[4];
  {
    const int jr = jb + lm;
#pragma unroll
    for (int kt = 0; kt < 5; ++kt)
      bw1[kt] = *reinterpret_cast<const bf16x8*>(W1b + (size_t)jr * 160 + kt * 32 + l4 * 8);
#pragma unroll
    for (int kt = 0; kt < 4; ++kt)
      bw2[kt] = *reinterpret_cast<const bf16x8*>(W2b + (size_t)jr * 128 + kt * 32 + l4 * 8);
  }
  // biases for C rows j = jb + l4*4 + rr
  float4 b1v = *reinterpret_cast<const float4*>(b1 + jb + l4 * 4);
  float4 b2v = *reinterpret_cast<const float4*>(b2 + jb + l4 * 4);
  const int* srcp = ei;
  const int* dstp = ei + E;

  for (int tile = blockIdx.x; tile < ntiles; tile += gridDim.x) {
    const int e0 = tile * TILE_E;

    // ---- stage A tile (swizzled) ----
#pragma unroll
    for (int it = 0; it < 2; ++it) {          // x: 1024 16B chunks
      int idx = it * 512 + tid;
      int e = idx >> 4, q = idx & 15;
      int s = srcp[e0 + e];
      bf16x8 v = *reinterpret_cast<const bf16x8*>(xb + (size_t)s * ND + q * 8);
      *reinterpret_cast<bf16x8*>(AlsB + e * 384 + ((q ^ (e & 7)) << 4)) = v;
    }
    {                                          // ea: 512 8B pieces
      int e = tid >> 3, q = tid & 7;
      float4 v = reinterpret_cast<const float4*>(ea)[(size_t)(e0 + e) * 8 + q];
      bf16x4 h;
      h[0] = (__bf16)v.x; h[1] = (__bf16)v.y; h[2] = (__bf16)v.z; h[3] = (__bf16)v.w;
      int chunk = 16 + (q >> 1);
      *reinterpret_cast<bf16x4*>(AlsB + e * 384 + ((chunk ^ (e & 7)) << 4) + ((q & 1) << 3)) = h;
    }
    if (SORT && tid < TILE_E) {                // stash spos in free chunk 20^sw
      int sp = spos[e0 + tid];
      *reinterpret_cast<int*>(AlsB + tid * 384 + ((20 ^ (tid & 7)) << 4)) = sp;
    }
    __syncthreads();

    // ---- layer 1: H1^T[j][e] = silu(W1 . A^T); packed b64 writes ----
#pragma unroll
    for (int et = 0; et < 4; ++et) {
      const int e = et * 16 + lm;
      const int sw = lm & 7;
      f32x4 acc = {0.f, 0.f, 0.f, 0.f};
#pragma unroll
      for (int kt = 0; kt < 5; ++kt) {
        bf16x8 bfrag = *reinterpret_cast<const bf16x8*>(AlsB + e * 384 + (((kt * 4 + l4) ^ sw) << 4));
        acc = mfma_bf16(bw1[kt], bfrag, acc);
      }
      bf16x4 h0;
#pragma unroll
      for (int rr = 0; rr < 4; ++rr)
        h0[rr] = (__bf16)fast_silu(acc[rr] + (&b1v.x)[rr]);
      int c0 = w * 2 + (l4 >> 1);
      int inner = (l4 & 1) << 3;
      *reinterpret_cast<bf16x4*>(H1B + e * 256 + ((c0 ^ sw) << 4) + inner) = h0;
    }
    __syncthreads();

    // ---- layer 2: M^T[j][e] = silu(W2 . H1^T); 8B stores to mbuf ----
#pragma unroll
    for (int et = 0; et < 4; ++et) {
      const int e = et * 16 + lm;
      const int sw = lm & 7;
      f32x4 acc = {0.f, 0.f, 0.f, 0.f};
#pragma unroll
      for (int kt = 0; kt < 4; ++kt) {
        bf16x8 bfrag = *reinterpret_cast<const bf16x8*>(H1B + e * 256 + (((kt * 4 + l4) ^ sw) << 4));
        acc = mfma_bf16(bw2[kt], bfrag, acc);
      }
      if (SORT) {
        bf16x4 m0;
#pragma unroll
        for (int rr = 0; rr < 4; ++rr)
          m0[rr] = (__bf16)fast_silu(acc[rr] + (&b2v.x)[rr]);
        int sp = *reinterpret_cast<const int*>(AlsB + e * 384 + ((20 ^ sw) << 4));
        *reinterpret_cast<bf16x4*>(mbuf + (size_t)sp * HID + jb + l4 * 4) = m0;
      } else {
        int d = dstp[e0 + e];
#pragma unroll
        for (int rr = 0; rr < 4; ++rr)
          atomicAdd(agg + (size_t)d * HID + jb + l4 * 4 + rr,
                    fast_silu(acc[rr] + (&b2v.x)[rr]));
      }
    }
    __syncthreads();
  }
}

// ================= aggregator: one wave per node =================
__global__ __launch_bounds__(256) void k_aggregate(
    const __bf16* __restrict__ mbuf, const int* __restrict__ offsets,
    __bf16* __restrict__ aggb, int N)
{
  int node = blockIdx.x * 4 + (threadIdx.x >> 6);
  int l = threadIdx.x & 63;
  if (node >= N) return;
  int lo = offsets[node], hi = offsets[node + 1];
  int cnt = hi - lo;
  float s0 = 0.f, s1 = 0.f;
  const uint32_t* p = reinterpret_cast<const uint32_t*>(mbuf) + (size_t)lo * 64 + l;
  int r = 0;
  for (; r + 4 <= cnt; r += 4) {
    uint32_t u0 = p[0], u1 = p[64], u2 = p[128], u3 = p[192];
    p += 256;
    s0 += __uint_as_float(u0 << 16) + __uint_as_float(u1 << 16)
        + __uint_as_float(u2 << 16) + __uint_as_float(u3 << 16);
    s1 += __uint_as_float(u0 & 0xffff0000u) + __uint_as_float(u1 & 0xffff0000u)
        + __uint_as_float(u2 & 0xffff0000u) + __uint_as_float(u3 & 0xffff0000u);
  }
  for (; r < cnt; ++r) {
    uint32_t u = p[0];
    p += 64;
    s0 += __uint_as_float(u << 16);
    s1 += __uint_as_float(u & 0xffff0000u);
  }
  uint32_t o = (uint32_t)__builtin_bit_cast(unsigned short, (__bf16)s0) |
               ((uint32_t)__builtin_bit_cast(unsigned short, (__bf16)s1) << 16);
  reinterpret_cast<uint32_t*>(aggb)[(size_t)node * 64 + l] = o;
}

// ================= GRU (weights-as-A, transposed, no LDS) =================
__global__ __launch_bounds__(512) void gru2(
    const __bf16* __restrict__ aggb,
    const __bf16* __restrict__ xb,
    const float*  __restrict__ x,
    const __bf16* __restrict__ Wih, const float* __restrict__ bih,  // [384,128]
    const __bf16* __restrict__ Whh, const float* __restrict__ bhh,
    float* __restrict__ out, int N)
{
  const int tid = threadIdx.x;
  const int w = tid >> 6, l = tid & 63;
  const int l4 = l >> 4, lm = l & 15;
  const int n0 = blockIdx.x * 64;
  const int jb = w * 16;
  const int jr = jb + lm, jz = jr + 128, jn = jr + 256;

  bf16x8 WiR[4], WhR[4], WiZ[4], WhZ[4], WiN[4], WhN[4];
#pragma unroll
  for (int kt = 0; kt < 4; ++kt) {
    int ko = kt * 32 + l4 * 8;
    WiR[kt] = *reinterpret_cast<const bf16x8*>(Wih + (size_t)jr * ND + ko);
    WhR[kt] = *reinterpret_cast<const bf16x8*>(Whh + (size_t)jr * ND + ko);
    WiZ[kt] = *reinterpret_cast<const bf16x8*>(Wih + (size_t)jz * ND + ko);
    WhZ[kt] = *reinterpret_cast<const bf16x8*>(Whh + (size_t)jz * ND + ko);
    WiN[kt] = *reinterpret_cast<const bf16x8*>(Wih + (size_t)jn * ND + ko);
    WhN[kt] = *reinterpret_cast<const bf16x8*>(Whh + (size_t)jn * ND + ko);
  }
  float4 birv, bizv, binv, bhnv;
  {
    int j0 = jb + l4 * 4;
    float4 a = *reinterpret_cast<const float4*>(bih + j0);
    float4 b = *reinterpret_cast<const float4*>(bhh + j0);
    birv = make_float4(a.x + b.x, a.y + b.y, a.z + b.z, a.w + b.w);
    a = *reinterpret_cast<const float4*>(bih + 128 + j0);
    b = *reinterpret_cast<const float4*>(bhh + 128 + j0);
    bizv = make_float4(a.x + b.x, a.y + b.y, a.z + b.z, a.w + b.w);
    binv = *reinterpret_cast<const float4*>(bih + 256 + j0);
    bhnv = *reinterpret_cast<const float4*>(bhh + 256 + j0);
  }

#pragma unroll
  for (int rt = 0; rt < 4; ++rt) {
    const int node = n0 + rt * 16 + lm;
    const bool ok = node < N;
    bf16x8 aA[4], aX[4];
#pragma unroll
    for (int kt = 0; kt < 4; ++kt) {
      int ko = kt * 32 + l4 * 8;
      bf16x8 z8 = {};
      aA[kt] = ok ? *reinterpret_cast<const bf16x8*>(aggb + (size_t)node * ND + ko) : z8;
      aX[kt] = ok ? *reinterpret_cast<const bf16x8*>(xb + (size_t)node * ND + ko) : z8;
    }
    f32x4 aR = {0.f,0.f,0.f,0.f}, aZ = {0.f,0.f,0.f,0.f};
    f32x4 ai = {0.f,0.f,0.f,0.f}, ah = {0.f,0.f,0.f,0.f};
#pragma unroll
    for (int kt = 0; kt < 4; ++kt) {
      aR = mfma_bf16(WiR[kt], aA[kt], aR);
      aR = mfma_bf16(WhR[kt], aX[kt], aR);
      aZ = mfma_bf16(WiZ[kt], aA[kt], aZ);
      aZ = mfma_bf16(WhZ[kt], aX[kt], aZ);
      ai = mfma_bf16(WiN[kt], aA[kt], ai);
      ah = mfma_bf16(WhN[kt], aX[kt], ah);
    }
    if (ok) {
      float4 xv = *reinterpret_cast<const float4*>(x + (size_t)node * ND + jb + l4 * 4);
      float4 ov;
#pragma unroll
      for (int rr = 0; rr < 4; ++rr) {
        float r = fast_sigmoid(aR[rr] + (&birv.x)[rr]);
        float z = fast_sigmoid(aZ[rr] + (&bizv.x)[rr]);
        float n = fast_tanh(ai[rr] + (&binv.x)[rr] + r * (ah[rr] + (&bhnv.x)[rr]));
        (&ov.x)[rr] = (1.f - z) * n + z * (&xv.x)[rr];
      }
      *reinterpret_cast<float4*>(out + (size_t)node * ND + jb + l4 * 4) = ov;
    }
  }
}

extern "C" void kernel_launch(void* const* d_in, const int* in_sizes, int n_in,
                              void* d_out, int out_size, void* d_ws, size_t ws_size,
                              hipStream_t stream) {
  const float* x   = (const float*)d_in[0];
  const int*   ei  = (const int*)d_in[1];
  const float* ea  = (const float*)d_in[2];
  const float* W1  = (const float*)d_in[3];
  const float* b1  = (const float*)d_in[4];
  const float* W2  = (const float*)d_in[5];
  const float* b2  = (const float*)d_in[6];
  const float* Wih = (const float*)d_in[7];
  const float* bih = (const float*)d_in[8];
  const float* Whh = (const float*)d_in[9];
  const float* bhh = (const float*)d_in[10];
  float* out = (float*)d_out;
  const int N = in_sizes[0] / ND;       // 50000
  const int E = in_sizes[1] / 2;        // 800000

  const int nb = (N + 255) / 256;
  const int nC = nb * 256;

  char* ws = (char*)d_ws;
  size_t off = 0;
  auto alloc = [&](size_t bytes) -> void* {
    void* p = ws + off;
    off += (bytes + 255) & ~(size_t)255;
    return p;
  };
  __bf16* xb   = (__bf16*)alloc((size_t)N * ND * 2);
  __bf16* aggb = (__bf16*)alloc((size_t)N * ND * 2);
  __bf16* W1b  = (__bf16*)alloc(128 * 160 * 2);
  __bf16* W2b  = (__bf16*)alloc(128 * 128 * 2);
  __bf16* Wihb = (__bf16*)alloc(384 * 128 * 2);
  __bf16* Whhb = (__bf16*)alloc(384 * 128 * 2);
  size_t common_off = off;

  int*    counts  = (int*)alloc((size_t)nC * 4);
  int*    offsets = (int*)alloc((size_t)(nC + 16) * 4);
  int*    cursor  = (int*)alloc((size_t)nC * 4);
  int*    bsum    = (int*)alloc(256 * 4);
  int*    spos    = (int*)alloc((size_t)E * 4);
  __bf16* mbuf    = (__bf16*)alloc((size_t)E * HID * 2);
  size_t need_sort = off;

  bool use_sort = (ws_size >= need_sort);

  const int n8_x = N * ND / 8, n8_1 = 128 * 160 / 8, n8_2 = 128 * 128 / 8, n8_g = 384 * 128 / 8;
  int c1 = n8_x, c2 = c1 + n8_1, c3 = c2 + n8_2, c4 = c3 + n8_g, c5 = c4 + n8_g;
  cvt_all<<<(c5 + 255) / 256, 256, 0, stream>>>(x, xb, c1, W1, W1b, c2, W2, W2b, c3,
                                                Wih, Wihb, c4, Whh, Whhb, c5);

  const int ntiles = E / TILE_E;
  const int* dstp = ei + E;

  if (use_sort) {
    hipMemsetAsync(counts, 0, (size_t)nC * 4, stream);
    k_hist<<<(E + 255) / 256, 256, 0, stream>>>(dstp, counts, E);
    k_blocksum<<<nb, 256, 0, stream>>>(counts, bsum);
    k_scan_bsum<<<1, 256, 0, stream>>>(bsum, nb);
    k_scan_write<<<nb, 256, 0, stream>>>(counts, bsum, offsets, cursor);
    k_spos<<<(E + 255) / 256, 256, 0, stream>>>(dstp, cursor, spos, E);
    edge_mlp<1><<<2500, 512, 0, stream>>>(xb, ei, ea, W1b, b1, W2b, b2,
                                          nullptr, mbuf, spos, E, ntiles);
    k_aggregate<<<(N + 3) / 4, 256, 0, stream>>>(mbuf, offsets, aggb, N);
  } else {
    off = common_off;
    float* aggf = (float*)alloc((size_t)N * ND * 4);
    hipMemsetAsync(aggf, 0, (size_t)N * ND * 4, stream);
    edge_mlp<0><<<2500, 512, 0, stream>>>(xb, ei, ea, W1b, b1, W2b, b2,
                                          aggf, nullptr, nullptr, E, ntiles);
    cvt_all<<<(n8_x + 255) / 256, 256, 0, stream>>>(aggf, aggb, n8_x,
                                                    nullptr, nullptr, n8_x,
                                                    nullptr, nullptr, n8_x,
                                                    nullptr, nullptr, n8_x,
                                                    nullptr, nullptr, n8_x);
  }

  gru2<<<(N + 63) / 64, 512, 0, stream>>>(aggb, xb, x, Wihb, bih, Whhb, bhh, out, N);
}

// Round 5
// 365.840 us; speedup vs baseline: 1.0663x; 1.0663x over previous
//
#include <hip/hip_runtime.h>
#include <hip/hip_bf16.h>
#include <cstdint>

typedef __bf16 bf16x8 __attribute__((ext_vector_type(8)));
typedef __bf16 bf16x4 __attribute__((ext_vector_type(4)));
typedef float  f32x4  __attribute__((ext_vector_type(4)));

#define ND 128
#define HID 128

__device__ __forceinline__ f32x4 mfma_bf16(bf16x8 a, bf16x8 b, f32x4 c) {
  return __builtin_amdgcn_mfma_f32_16x16x32_bf16(a, b, c, 0, 0, 0);
}
__device__ __forceinline__ float fast_sigmoid(float x) {
  return __fdividef(1.f, 1.f + __expf(-x));
}
__device__ __forceinline__ float fast_silu(float x) {
  return __fdividef(x, 1.f + __expf(-x));
}
__device__ __forceinline__ float fast_tanh(float x) {
  float cx = fminf(fmaxf(x, -15.f), 15.f);
  float e = __expf(2.f * cx);
  return __fdividef(e - 1.f, e + 1.f);
}

// ---- fused f32 -> bf16 conversion over 5 segments ----
__global__ void cvt_all(const float* __restrict__ s0, __bf16* __restrict__ d0, int c1,
                        const float* __restrict__ s1, __bf16* __restrict__ d1, int c2,
                        const float* __restrict__ s2, __bf16* __restrict__ d2, int c3,
                        const float* __restrict__ s3, __bf16* __restrict__ d3, int c4,
                        const float* __restrict__ s4, __bf16* __restrict__ d4, int c5) {
  int i = blockIdx.x * blockDim.x + threadIdx.x;
  const float* s; __bf16* d; int j;
  if (i < c1)      { s = s0; d = d0; j = i; }
  else if (i < c2) { s = s1; d = d1; j = i - c1; }
  else if (i < c3) { s = s2; d = d2; j = i - c2; }
  else if (i < c4) { s = s3; d = d3; j = i - c3; }
  else if (i < c5) { s = s4; d = d4; j = i - c4; }
  else return;
  const float4* sp = reinterpret_cast<const float4*>(s) + (size_t)j * 2;
  float4 a = sp[0], b = sp[1];
  bf16x8 v;
  v[0] = (__bf16)a.x; v[1] = (__bf16)a.y; v[2] = (__bf16)a.z; v[3] = (__bf16)a.w;
  v[4] = (__bf16)b.x; v[5] = (__bf16)b.y; v[6] = (__bf16)b.z; v[7] = (__bf16)b.w;
  reinterpret_cast<bf16x8*>(d)[j] = v;
}

// ================= sort machinery =================
__global__ void k_hist(const int* __restrict__ dst, int* __restrict__ counts, int E) {
  int e = blockIdx.x * 256 + threadIdx.x;
  if (e < E) atomicAdd(&counts[dst[e]], 1);
}

__global__ void k_blocksum(const int* __restrict__ counts, int* __restrict__ bsum) {
  __shared__ int sd[256];
  int t = threadIdx.x;
  sd[t] = counts[blockIdx.x * 256 + t];
  __syncthreads();
  for (int d = 128; d > 0; d >>= 1) { if (t < d) sd[t] += sd[t + d]; __syncthreads(); }
  if (!t) bsum[blockIdx.x] = sd[0];
}

__global__ void k_scan_bsum(int* __restrict__ bsum, int nb) {
  __shared__ int sd[256];
  int t = threadIdx.x;
  int v = (t < nb) ? bsum[t] : 0;
  sd[t] = v;
  __syncthreads();
  for (int d = 1; d < 256; d <<= 1) {
    int u = (t >= d) ? sd[t - d] : 0;
    __syncthreads();
    sd[t] += u;
    __syncthreads();
  }
  if (t < nb) bsum[t] = sd[t] - v;
}

__global__ void k_scan_write(const int* __restrict__ counts, const int* __restrict__ bsum,
                             int* __restrict__ cursor) {
  __shared__ int sd[256];
  int t = threadIdx.x, b = blockIdx.x;
  int i = b * 256 + t;
  int c = counts[i];
  sd[t] = c;
  __syncthreads();
  for (int d = 1; d < 256; d <<= 1) {
    int u = (t >= d) ? sd[t - d] : 0;
    __syncthreads();
    sd[t] += u;
    __syncthreads();
  }
  cursor[i] = bsum[b] + sd[t] - c;   // exclusive prefix
}

__global__ void k_perm(const int* __restrict__ dst, int* __restrict__ cursor,
                       int* __restrict__ eperm, int* __restrict__ dsorted, int E) {
  int e = blockIdx.x * 256 + threadIdx.x;
  if (e < E) {
    int d = dst[e];
    int p = atomicAdd(&cursor[d], 1);
    eperm[p] = e;
    dsorted[p] = d;
  }
}

// ================= fused edge MLP + aggregate =================
// Edges processed in dst-sorted slot order. 8 waves, wave w owns j-strip
// [w*16, w*16+16). A tile: [64 slots][320B] (chunks 0..15 = x swizzled ^sw,
// 16..19 = ea swizzled ^(sw&3)). H1 tile: [64][256B] chunks ^sw. M tile
// (layer-2 out) overlays A region as [64][256B]. Segmented-scan flush
// atomically adds per-node partial sums into agg (f32).
#define TILE_E 64

__global__ __launch_bounds__(512, 4) void edge_mlp2(
    const __bf16* __restrict__ xb,
    const int*    __restrict__ srcp,     // [E]
    const float*  __restrict__ ea,       // [E,32]
    const __bf16* __restrict__ W1b,      // [128,160]
    const float*  __restrict__ b1,
    const __bf16* __restrict__ W2b,      // [128,128]
    const float*  __restrict__ b2,
    const int*    __restrict__ eperm,    // [E] slot -> edge
    const int*    __restrict__ dsorted,  // [E] slot -> dst node
    float* __restrict__ agg,             // [N,128] f32, zeroed
    int ntiles)
{
  __shared__ __bf16 Als[TILE_E * 160];   // 20 KB, 320B rows; first 16KB reused as M
  __shared__ __bf16 H1[TILE_E * 128];    // 16 KB, 256B rows
  __shared__ int dstls[TILE_E];
  char* AB = (char*)Als;
  char* HB = (char*)H1;

  const int tid = threadIdx.x;
  const int w  = tid >> 6;
  const int l  = tid & 63;
  const int l4 = l >> 4;
  const int lm = l & 15;
  const int jb = w * 16;

  // weight fragments (A operand): row j = jb+lm, k = kt*32 + l4*8
  bf16x8 bw1[5], bw2[4];
  {
    const int jr = jb + lm;
#pragma unroll
    for (int kt = 0; kt < 5; ++kt)
      bw1[kt] = *reinterpret_cast<const bf16x8*>(W1b + (size_t)jr * 160 + kt * 32 + l4 * 8);
#pragma unroll
    for (int kt = 0; kt < 4; ++kt)
      bw2[kt] = *reinterpret_cast<const bf16x8*>(W2b + (size_t)jr * 128 + kt * 32 + l4 * 8);
  }
  const float4 b1v = *reinterpret_cast<const float4*>(b1 + jb + l4 * 4);
  const float4 b2v = *reinterpret_cast<const float4*>(b2 + jb + l4 * 4);

  // flush-phase constants: thread covers column fj, slot group fg
  const int fj = tid & 127;
  const int fg = tid >> 7;          // 0..3 (each wave entirely in one group)
  const int fchunk = fj >> 3;
  const int finner = (fj & 7) * 2;

  // staging thread mapping
  const int xslot = tid >> 4, xq = tid & 15;     // x: 2 chunks (slots xslot, xslot+32)
  const int aslot = tid >> 3, aq = tid & 7;      // ea: 1 float4

  // prefetch registers
  bf16x8 pxv0 = {}, pxv1 = {};
  float4 pea_ = {};
  int pdst_ = 0;

  auto PREFETCH = [&](int t) {
    int p0 = t * TILE_E;
    int e0i = eperm[p0 + xslot];
    int e1i = eperm[p0 + xslot + 32];
    int s0 = srcp[e0i];
    int s1 = srcp[e1i];
    pxv0 = *reinterpret_cast<const bf16x8*>(xb + (size_t)s0 * ND + xq * 8);
    pxv1 = *reinterpret_cast<const bf16x8*>(xb + (size_t)s1 * ND + xq * 8);
    int e2i = eperm[p0 + aslot];
    pea_ = reinterpret_cast<const float4*>(ea)[(size_t)e2i * 8 + aq];
    if (tid < TILE_E) pdst_ = dsorted[p0 + tid];
  };

  int tile = blockIdx.x;
  if (tile < ntiles) PREFETCH(tile);

  for (; tile < ntiles; tile += gridDim.x) {
    __syncthreads();   // prev iteration's flush done before overwriting A/dstls

    // ---- write staged regs -> LDS ----
    {
      int s_ = xslot;
      *reinterpret_cast<bf16x8*>(AB + s_ * 320 + ((xq ^ (s_ & 7)) << 4)) = pxv0;
      int s2 = xslot + 32;
      *reinterpret_cast<bf16x8*>(AB + s2 * 320 + ((xq ^ (s2 & 7)) << 4)) = pxv1;
    }
    {
      bf16x4 h;
      h[0] = (__bf16)pea_.x; h[1] = (__bf16)pea_.y;
      h[2] = (__bf16)pea_.z; h[3] = (__bf16)pea_.w;
      int pc = 16 + ((aq >> 1) ^ (aslot & 3));
      *reinterpret_cast<bf16x4*>(AB + aslot * 320 + (pc << 4) + ((aq & 1) << 3)) = h;
    }
    if (tid < TILE_E) dstls[tid] = pdst_;
    __syncthreads();

    // ---- prefetch next tile (hidden under L1+L2 compute) ----
    int nt = tile + gridDim.x;
    if (nt < ntiles) PREFETCH(nt);

    // ---- layer 1: H1^T[j][slot] = silu(W1 . A^T) ----
#pragma unroll
    for (int et = 0; et < 4; ++et) {
      const int s_ = et * 16 + lm;
      const int sw = s_ & 7;
      f32x4 acc = {0.f, 0.f, 0.f, 0.f};
#pragma unroll
      for (int kt = 0; kt < 4; ++kt) {
        bf16x8 bfrag = *reinterpret_cast<const bf16x8*>(AB + s_ * 320 + (((kt * 4 + l4) ^ sw) << 4));
        acc = mfma_bf16(bw1[kt], bfrag, acc);
      }
      {
        bf16x8 bfrag = *reinterpret_cast<const bf16x8*>(AB + s_ * 320 + ((16 + (l4 ^ (s_ & 3))) << 4));
        acc = mfma_bf16(bw1[4], bfrag, acc);
      }
      bf16x4 h0;
#pragma unroll
      for (int rr = 0; rr < 4; ++rr)
        h0[rr] = (__bf16)fast_silu(acc[rr] + (&b1v.x)[rr]);
      int c0 = w * 2 + (l4 >> 1);
      int inner = (l4 & 1) << 3;
      *reinterpret_cast<bf16x4*>(HB + s_ * 256 + ((c0 ^ sw) << 4) + inner) = h0;
    }
    __syncthreads();

    // ---- layer 2: M^T[j][slot] = silu(W2 . H1^T) -> M tile in A region ----
#pragma unroll
    for (int et = 0; et < 4; ++et) {
      const int s_ = et * 16 + lm;
      const int sw = s_ & 7;
      f32x4 acc = {0.f, 0.f, 0.f, 0.f};
#pragma unroll
      for (int kt = 0; kt < 4; ++kt) {
        bf16x8 bfrag = *reinterpret_cast<const bf16x8*>(HB + s_ * 256 + (((kt * 4 + l4) ^ sw) << 4));
        acc = mfma_bf16(bw2[kt], bfrag, acc);
      }
      bf16x4 m0;
#pragma unroll
      for (int rr = 0; rr < 4; ++rr)
        m0[rr] = (__bf16)fast_silu(acc[rr] + (&b2v.x)[rr]);
      int c0 = w * 2 + (l4 >> 1);
      int inner = (l4 & 1) << 3;
      *reinterpret_cast<bf16x4*>(AB + s_ * 256 + ((c0 ^ sw) << 4) + inner) = m0;
    }
    __syncthreads();

    // ---- segmented flush: sum runs of equal dst, one atomicAdd per segment ----
    {
      float acc = 0.f;
      int cur = dstls[fg * 16];
#pragma unroll
      for (int i = 0; i < 16; ++i) {
        int slot = fg * 16 + i;
        int nd = dstls[slot];
        if (nd != cur) {
          atomicAdd(agg + (size_t)cur * HID + fj, acc);
          acc = 0.f;
          cur = nd;
        }
        uint32_t raw = *reinterpret_cast<const uint16_t*>(
            AB + slot * 256 + ((fchunk ^ (slot & 7)) << 4) + finner);
        acc += __uint_as_float(raw << 16);
      }
      atomicAdd(agg + (size_t)cur * HID + fj, acc);
    }
  }
}

// ================= GRU (weights-as-A, transposed, no LDS) =================
__global__ __launch_bounds__(512) void gru2(
    const float*  __restrict__ agg,      // [N,128] f32
    const __bf16* __restrict__ xb,
    const float*  __restrict__ x,
    const __bf16* __restrict__ Wih, const float* __restrict__ bih,  // [384,128]
    const __bf16* __restrict__ Whh, const float* __restrict__ bhh,
    float* __restrict__ out, int N)
{
  const int tid = threadIdx.x;
  const int w = tid >> 6, l = tid & 63;
  const int l4 = l >> 4, lm = l & 15;
  const int n0 = blockIdx.x * 64;
  const int jb = w * 16;
  const int jr = jb + lm, jz = jr + 128, jn = jr + 256;

  bf16x8 WiR[4], WhR[4], WiZ[4], WhZ[4], WiN[4], WhN[4];
#pragma unroll
  for (int kt = 0; kt < 4; ++kt) {
    int ko = kt * 32 + l4 * 8;
    WiR[kt] = *reinterpret_cast<const bf16x8*>(Wih + (size_t)jr * ND + ko);
    WhR[kt] = *reinterpret_cast<const bf16x8*>(Whh + (size_t)jr * ND + ko);
    WiZ[kt] = *reinterpret_cast<const bf16x8*>(Wih + (size_t)jz * ND + ko);
    WhZ[kt] = *reinterpret_cast<const bf16x8*>(Whh + (size_t)jz * ND + ko);
    WiN[kt] = *reinterpret_cast<const bf16x8*>(Wih + (size_t)jn * ND + ko);
    WhN[kt] = *reinterpret_cast<const bf16x8*>(Whh + (size_t)jn * ND + ko);
  }
  float4 birv, bizv, binv, bhnv;
  {
    int j0 = jb + l4 * 4;
    float4 a = *reinterpret_cast<const float4*>(bih + j0);
    float4 b = *reinterpret_cast<const float4*>(bhh + j0);
    birv = make_float4(a.x + b.x, a.y + b.y, a.z + b.z, a.w + b.w);
    a = *reinterpret_cast<const float4*>(bih + 128 + j0);
    b = *reinterpret_cast<const float4*>(bhh + 128 + j0);
    bizv = make_float4(a.x + b.x, a.y + b.y, a.z + b.z, a.w + b.w);
    binv = *reinterpret_cast<const float4*>(bih + 256 + j0);
    bhnv = *reinterpret_cast<const float4*>(bhh + 256 + j0);
  }

#pragma unroll
  for (int rt = 0; rt < 4; ++rt) {
    const int node = n0 + rt * 16 + lm;
    const bool ok = node < N;
    bf16x8 aA[4], aX[4];
#pragma unroll
    for (int kt = 0; kt < 4; ++kt) {
      int ko = kt * 32 + l4 * 8;
      bf16x8 z8 = {};
      if (ok) {
        float4 a0 = *reinterpret_cast<const float4*>(agg + (size_t)node * ND + ko);
        float4 a1 = *reinterpret_cast<const float4*>(agg + (size_t)node * ND + ko + 4);
        bf16x8 v;
        v[0] = (__bf16)a0.x; v[1] = (__bf16)a0.y; v[2] = (__bf16)a0.z; v[3] = (__bf16)a0.w;
        v[4] = (__bf16)a1.x; v[5] = (__bf16)a1.y; v[6] = (__bf16)a1.z; v[7] = (__bf16)a1.w;
        aA[kt] = v;
        aX[kt] = *reinterpret_cast<const bf16x8*>(xb + (size_t)node * ND + ko);
      } else {
        aA[kt] = z8;
        aX[kt] = z8;
      }
    }
    f32x4 aR = {0.f,0.f,0.f,0.f}, aZ = {0.f,0.f,0.f,0.f};
    f32x4 ai = {0.f,0.f,0.f,0.f}, ah = {0.f,0.f,0.f,0.f};
#pragma unroll
    for (int kt = 0; kt < 4; ++kt) {
      aR = mfma_bf16(WiR[kt], aA[kt], aR);
      aR = mfma_bf16(WhR[kt], aX[kt], aR);
      aZ = mfma_bf16(WiZ[kt], aA[kt], aZ);
      aZ = mfma_bf16(WhZ[kt], aX[kt], aZ);
      ai = mfma_bf16(WiN[kt], aA[kt], ai);
      ah = mfma_bf16(WhN[kt], aX[kt], ah);
    }
    if (ok) {
      float4 xv = *reinterpret_cast<const float4*>(x + (size_t)node * ND + jb + l4 * 4);
      float4 ov;
#pragma unroll
      for (int rr = 0; rr < 4; ++rr) {
        float r = fast_sigmoid(aR[rr] + (&birv.x)[rr]);
        float z = fast_sigmoid(aZ[rr] + (&bizv.x)[rr]);
        float n = fast_tanh(ai[rr] + (&binv.x)[rr] + r * (ah[rr] + (&bhnv.x)[rr]));
        (&ov.x)[rr] = (1.f - z) * n + z * (&xv.x)[rr];
      }
      *reinterpret_cast<float4*>(out + (size_t)node * ND + jb + l4 * 4) = ov;
    }
  }
}

extern "C" void kernel_launch(void* const* d_in, const int* in_sizes, int n_in,
                              void* d_out, int out_size, void* d_ws, size_t ws_size,
                              hipStream_t stream) {
  const float* x   = (const float*)d_in[0];
  const int*   ei  = (const int*)d_in[1];
  const float* ea  = (const float*)d_in[2];
  const float* W1  = (const float*)d_in[3];
  const float* b1  = (const float*)d_in[4];
  const float* W2  = (const float*)d_in[5];
  const float* b2  = (const float*)d_in[6];
  const float* Wih = (const float*)d_in[7];
  const float* bih = (const float*)d_in[8];
  const float* Whh = (const float*)d_in[9];
  const float* bhh = (const float*)d_in[10];
  float* out = (float*)d_out;
  const int N = in_sizes[0] / ND;       // 50000
  const int E = in_sizes[1] / 2;        // 800000

  const int nb = (N + 255) / 256;
  const int nC = nb * 256;

  char* ws = (char*)d_ws;
  size_t off = 0;
  auto alloc = [&](size_t bytes) -> void* {
    void* p = ws + off;
    off += (bytes + 255) & ~(size_t)255;
    return p;
  };
  __bf16* xb      = (__bf16*)alloc((size_t)N * ND * 2);
  __bf16* W1b     = (__bf16*)alloc(128 * 160 * 2);
  __bf16* W2b     = (__bf16*)alloc(128 * 128 * 2);
  __bf16* Wihb    = (__bf16*)alloc(384 * 128 * 2);
  __bf16* Whhb    = (__bf16*)alloc(384 * 128 * 2);
  int*    counts  = (int*)alloc((size_t)nC * 4);
  int*    cursor  = (int*)alloc((size_t)nC * 4);
  int*    bsum    = (int*)alloc(256 * 4);
  int*    eperm   = (int*)alloc((size_t)E * 4);
  int*    dsorted = (int*)alloc((size_t)E * 4);
  float*  agg     = (float*)alloc((size_t)N * ND * 4);
  (void)ws_size;

  const int* srcp = ei;
  const int* dstp = ei + E;

  hipMemsetAsync(agg, 0, (size_t)N * ND * 4, stream);
  hipMemsetAsync(counts, 0, (size_t)nC * 4, stream);

  const int n8_x = N * ND / 8, n8_1 = 128 * 160 / 8, n8_2 = 128 * 128 / 8, n8_g = 384 * 128 / 8;
  int c1 = n8_x, c2 = c1 + n8_1, c3 = c2 + n8_2, c4 = c3 + n8_g, c5 = c4 + n8_g;
  cvt_all<<<(c5 + 255) / 256, 256, 0, stream>>>(x, xb, c1, W1, W1b, c2, W2, W2b, c3,
                                                Wih, Wihb, c4, Whh, Whhb, c5);

  k_hist<<<(E + 255) / 256, 256, 0, stream>>>(dstp, counts, E);
  k_blocksum<<<nb, 256, 0, stream>>>(counts, bsum);
  k_scan_bsum<<<1, 256, 0, stream>>>(bsum, nb);
  k_scan_write<<<nb, 256, 0, stream>>>(counts, bsum, cursor);
  k_perm<<<(E + 255) / 256, 256, 0, stream>>>(dstp, cursor, eperm, dsorted, E);

  const int ntiles = E / TILE_E;   // 12500
  edge_mlp2<<<2500, 512, 0, stream>>>(xb, srcp, ea, W1b, b1, W2b, b2,
                                      eperm, dsorted, agg, ntiles);

  gru2<<<(N + 63) / 64, 512, 0, stream>>>(agg, xb, x, Wihb, bih, Whhb, bhh, out, N);
}